// Round 1
// baseline (302.709 us; speedup 1.0000x reference)
//
#include <hip/hip_runtime.h>

#define DEVI __device__ __forceinline__

typedef _Float16 f16x8 __attribute__((ext_vector_type(8)));
typedef _Float16 f16x4v __attribute__((ext_vector_type(4)));
typedef _Float16 f16x2 __attribute__((ext_vector_type(2)));
typedef float f32x4 __attribute__((ext_vector_type(4)));

DEVI void gl16(const void* g, void* l) {
  __builtin_amdgcn_global_load_lds((const __attribute__((address_space(1))) void*)g,
                                   (__attribute__((address_space(3))) void*)l, 16, 0, 0);
}

// ---------------- f32 -> f16 convert ----------------
__global__ __launch_bounds__(256) void k_cvt(const float* __restrict__ in, _Float16* __restrict__ out, int n4) {
  int i = blockIdx.x * 256 + threadIdx.x;
  int stride = gridDim.x * 256;
  for (; i < n4; i += stride) {
    float4 v = ((const float4*)in)[i];
    f16x4v h = { (_Float16)v.x, (_Float16)v.y, (_Float16)v.z, (_Float16)v.w };
    ((f16x4v*)out)[i] = h;
  }
}

// ---------------- transpose + convert: in[R][C] f32 -> out[C][R] f16 ----------------
__global__ __launch_bounds__(256) void k_transpose(const float* __restrict__ in, _Float16* __restrict__ out,
                                                   int R, int C) {
  __shared__ float t[32][33];
  int cb = blockIdx.x * 32, rb = blockIdx.y * 32;
  int tx = threadIdx.x & 31, ty = threadIdx.x >> 5;
  #pragma unroll
  for (int i = ty; i < 32; i += 8) t[i][tx] = in[(size_t)(rb + i) * C + cb + tx];
  __syncthreads();
  #pragma unroll
  for (int i = ty; i < 32; i += 8) out[(size_t)(cb + i) * R + rb + tx] = (_Float16)t[tx][i];
}

// ---------------- GEMM: C[M,N] = A[M,K] * BT[N,K]^T + bias ----------------
// EPI=0: write fp32 outF.  EPI=1: scatter q/k/v (q scaled by 1/sqrt(80)).
template<int M, int N, int K, int EPI>
__global__ __launch_bounds__(256) void k_gemm(const _Float16* __restrict__ A, const _Float16* __restrict__ BT,
                                              const float* __restrict__ bias, float* __restrict__ outF,
                                              _Float16* __restrict__ qo, _Float16* __restrict__ ko,
                                              _Float16* __restrict__ vo) {
  __shared__ _Float16 Al[128 * 32];
  __shared__ _Float16 Bl[128 * 32];
  const int tid = threadIdx.x;
  const int w = tid >> 6, lane = tid & 63, ln = lane & 15, g = lane >> 4;
  const int bm0 = blockIdx.x * 128, bn0 = blockIdx.y * 128;
  const int wm = (w >> 1) * 64, wn = (w & 1) * 64;
  const int r0 = tid >> 2, c0 = (tid & 3) * 8;   // 16B chunk: row r0, elem-col c0; second issue row r0+64
  f32x4 acc[4][4] = {};
  for (int kt = 0; kt < K; kt += 32) {
    __syncthreads();
    gl16(&A[(size_t)(bm0 + r0) * K + kt + c0],      &Al[(w * 64) * 8]);
    gl16(&A[(size_t)(bm0 + r0 + 64) * K + kt + c0], &Al[(256 + w * 64) * 8]);
    gl16(&BT[(size_t)(bn0 + r0) * K + kt + c0],      &Bl[(w * 64) * 8]);
    gl16(&BT[(size_t)(bn0 + r0 + 64) * K + kt + c0], &Bl[(256 + w * 64) * 8]);
    __syncthreads();
    f16x8 af[4], bf[4];
    #pragma unroll
    for (int i = 0; i < 4; i++) af[i] = *(const f16x8*)&Al[(wm + i * 16 + ln) * 32 + g * 8];
    #pragma unroll
    for (int i = 0; i < 4; i++) bf[i] = *(const f16x8*)&Bl[(wn + i * 16 + ln) * 32 + g * 8];
    #pragma unroll
    for (int i = 0; i < 4; i++)
      #pragma unroll
      for (int j = 0; j < 4; j++)
        acc[i][j] = __builtin_amdgcn_mfma_f32_16x16x32_f16(af[i], bf[j], acc[i][j], 0, 0, 0);
  }
  if (EPI == 0) {
    #pragma unroll
    for (int j = 0; j < 4; j++) {
      int col = bn0 + wn + j * 16 + ln;
      float bv = bias[col];
      #pragma unroll
      for (int i = 0; i < 4; i++) {
        int mb = bm0 + wm + i * 16 + 4 * g;
        #pragma unroll
        for (int r = 0; r < 4; r++)
          outF[(size_t)(mb + r) * N + col] = acc[i][j][r] + bv;
      }
    }
  } else {
    #pragma unroll
    for (int j = 0; j < 4; j++) {
      int col = bn0 + wn + j * 16 + ln;
      float bv = bias[col];
      int h = col / 240;
      int tt = col - h * 240;
      int reg = tt / 80;
      int cc = tt - reg * 80;
      #pragma unroll
      for (int i = 0; i < 4; i++) {
        #pragma unroll
        for (int r = 0; r < 4; r++) {
          int m = bm0 + wm + i * 16 + 4 * g + r;
          int s = m >> 3, bb = m & 7;
          int head = bb * 16 + h;
          float val = acc[i][j][r] + bv;
          if (reg == 0)      qo[(head * 1024 + s) * 96 + cc] = (_Float16)(val * 0.11180339887498948f);
          else if (reg == 1) ko[(head * 1024 + s) * 96 + cc] = (_Float16)val;
          else               vo[(head * 1024 + s) * 80 + cc] = (_Float16)val;
        }
      }
    }
  }
}

// ---------------- per-head V transpose: vb[head][1024][80] -> vT[head][80][1024] ----------------
__global__ __launch_bounds__(256) void k_vtrans(const _Float16* __restrict__ vb, _Float16* __restrict__ vT) {
  __shared__ _Float16 t[64][81];
  int head = blockIdx.x >> 4;
  int sb = (blockIdx.x & 15) * 64;
  for (int idx = threadIdx.x; idx < 64 * 80; idx += 256) {
    int s = idx / 80, d = idx - s * 80;
    t[s][d] = vb[(head * 1024 + sb + s) * 80 + d];
  }
  __syncthreads();
  for (int idx = threadIdx.x; idx < 80 * 64; idx += 256) {
    int d = idx >> 6, s = idx & 63;
    vT[(head * 80 + d) * 1024 + sb + s] = t[s][d];
  }
}

// ---------------- flash attention ----------------
// qb/kb: [head][1024][96] (f16, cols 80..95 zero; q pre-scaled), vT: [head][80][1024]
// ctxg: [s][b][h*80+d] f16  == [8192][1280]
__global__ __launch_bounds__(256) void k_attn(const _Float16* __restrict__ qb, const _Float16* __restrict__ kb,
                                              const _Float16* __restrict__ vT, _Float16* __restrict__ ctxg) {
  __shared__ _Float16 Kl[64 * 104];
  __shared__ _Float16 Vl[80 * 72];
  __shared__ _Float16 Pl[64 * 72];
  const int tid = threadIdx.x;
  const int w = tid >> 6, lane = tid & 63, ln = lane & 15, g = lane >> 4;
  const int head = blockIdx.x >> 4;
  const int s0 = (blockIdx.x & 15) * 64;
  const int bb = head >> 4, h = head & 15;

  const int qrow = s0 + w * 16 + ln;
  f16x8 qf[3];
  #pragma unroll
  for (int dc = 0; dc < 3; ++dc)
    qf[dc] = *(const f16x8*)&qb[(head * 1024 + qrow) * 96 + dc * 32 + g * 8];

  f32x4 ctxa[5] = {};
  float m_run = -INFINITY, l_run = 0.f;

  for (int kt2 = 0; kt2 < 16; ++kt2) {
    __syncthreads();
    // stage K tile [64][96] -> Kl (stride 104)
    #pragma unroll
    for (int jj = 0; jj < 3; ++jj) {
      int c = tid + jj * 256;
      int row = c / 12, ch = c - row * 12;
      *(uint4*)&Kl[row * 104 + ch * 8] = *(const uint4*)&kb[(head * 1024 + kt2 * 64 + row) * 96 + ch * 8];
    }
    // stage V^T tile [80][64] -> Vl (stride 72)
    #pragma unroll
    for (int jj = 0; jj < 3; ++jj) {
      int c = tid + jj * 256;
      if (c < 640) {
        int row = c >> 3, ch = c & 7;
        *(uint4*)&Vl[row * 72 + ch * 8] = *(const uint4*)&vT[(head * 80 + row) * 1024 + kt2 * 64 + ch * 8];
      }
    }
    __syncthreads();
    // T = K * Q^T : sc[t16] holds rows kk = t16*16+4g+r, col q = ln (per wave)
    f32x4 sc[4] = {};
    #pragma unroll
    for (int t16 = 0; t16 < 4; ++t16)
      #pragma unroll
      for (int dc = 0; dc < 3; ++dc) {
        f16x8 kf = *(const f16x8*)&Kl[(t16 * 16 + ln) * 104 + dc * 32 + g * 8];
        sc[t16] = __builtin_amdgcn_mfma_f32_16x16x32_f16(kf, qf[dc], sc[t16], 0, 0, 0);
      }
    // online softmax over kk; per-lane col q = ln, 4 lanes (g=0..3) partition kk
    float tm = -INFINITY;
    #pragma unroll
    for (int t16 = 0; t16 < 4; ++t16)
      #pragma unroll
      for (int r = 0; r < 4; ++r) tm = fmaxf(tm, sc[t16][r]);
    tm = fmaxf(tm, __shfl_xor(tm, 16));
    tm = fmaxf(tm, __shfl_xor(tm, 32));
    float mnew = fmaxf(m_run, tm);
    float fac = __expf(m_run - mnew);
    float ps = 0.f;
    #pragma unroll
    for (int t16 = 0; t16 < 4; ++t16) {
      float p0 = __expf(sc[t16][0] - mnew);
      float p1 = __expf(sc[t16][1] - mnew);
      float p2 = __expf(sc[t16][2] - mnew);
      float p3 = __expf(sc[t16][3] - mnew);
      ps += (p0 + p1) + (p2 + p3);
      int off = (w * 16 + ln) * 72 + t16 * 16 + g * 4;
      f16x2 w01 = { (_Float16)p0, (_Float16)p1 };
      f16x2 w23 = { (_Float16)p2, (_Float16)p3 };
      *(f16x2*)&Pl[off] = w01;
      *(f16x2*)&Pl[off + 2] = w23;
    }
    ps += __shfl_xor(ps, 16);
    ps += __shfl_xor(ps, 32);
    l_run = l_run * fac + ps;
    m_run = mnew;
    // rescale ctx accumulators (rows q = 4g+r)
    #pragma unroll
    for (int r = 0; r < 4; ++r) {
      float fr = __shfl(fac, 4 * g + r);
      #pragma unroll
      for (int nt = 0; nt < 5; ++nt) ctxa[nt][r] *= fr;
    }
    // PV: ctx[q][d] += P[q][kk] * V[kk][d]
    #pragma unroll
    for (int kb4 = 0; kb4 < 2; ++kb4) {
      f16x8 pf = *(const f16x8*)&Pl[(w * 16 + ln) * 72 + kb4 * 32 + g * 8];
      #pragma unroll
      for (int nt = 0; nt < 5; ++nt) {
        f16x8 vf = *(const f16x8*)&Vl[(nt * 16 + ln) * 72 + kb4 * 32 + g * 8];
        ctxa[nt] = __builtin_amdgcn_mfma_f32_16x16x32_f16(pf, vf, ctxa[nt], 0, 0, 0);
      }
    }
  }
  // epilogue: divide by l, store ctx as f16 [s][b][h*80+d]
  #pragma unroll
  for (int r = 0; r < 4; ++r) {
    float lr = __shfl(l_run, 4 * g + r);
    float inv = 1.f / lr;
    int s = s0 + w * 16 + 4 * g + r;
    int base = (s * 8 + bb) * 1280 + h * 80;
    #pragma unroll
    for (int nt = 0; nt < 5; ++nt)
      ctxg[base + nt * 16 + ln] = (_Float16)(ctxa[nt][r] * inv);
  }
}

extern "C" void kernel_launch(void* const* d_in, const int* in_sizes, int n_in,
                              void* d_out, int out_size, void* d_ws, size_t ws_size,
                              hipStream_t stream) {
  const float* x     = (const float*)d_in[0];
  const float* w_in  = (const float*)d_in[1];
  const float* b_in  = (const float*)d_in[2];
  const float* w_out = (const float*)d_in[3];
  const float* b_out = (const float*)d_in[4];
  float* out = (float*)d_out;

  char* ws = (char*)d_ws;
  size_t off = 0;
  auto carve = [&](size_t bytes) -> void* {
    void* p = ws + off;
    off += (bytes + 255) & ~(size_t)255;
    return p;
  };
  _Float16* xb     = (_Float16*)carve(8192ull * 1280 * 2);
  _Float16* w_inT  = (_Float16*)carve(3840ull * 1280 * 2);
  _Float16* w_outT = (_Float16*)carve(1280ull * 1280 * 2);
  _Float16* qb     = (_Float16*)carve(128ull * 1024 * 96 * 2);
  _Float16* kbuf   = (_Float16*)carve(128ull * 1024 * 96 * 2);
  _Float16* vb     = (_Float16*)carve(128ull * 1024 * 80 * 2);
  _Float16* vT     = (_Float16*)carve(128ull * 1024 * 80 * 2);
  _Float16* ctxg   = (_Float16*)carve(8192ull * 1280 * 2);
  if (off > ws_size) return;  // workspace too small: fail loudly (output stays zero)

  hipMemsetAsync(qb, 0, 128ull * 1024 * 96 * 2, stream);
  hipMemsetAsync(kbuf, 0, 128ull * 1024 * 96 * 2, stream);

  k_cvt<<<2048, 256, 0, stream>>>(x, xb, 8192 * 1280 / 4);
  k_transpose<<<dim3(120, 40), 256, 0, stream>>>(w_in, w_inT, 1280, 3840);
  k_transpose<<<dim3(40, 40), 256, 0, stream>>>(w_out, w_outT, 1280, 1280);

  k_gemm<8192, 3840, 1280, 1><<<dim3(64, 30), 256, 0, stream>>>(xb, w_inT, b_in, nullptr, qb, kbuf, vb);
  k_vtrans<<<2048, 256, 0, stream>>>(vb, vT);
  k_attn<<<2048, 256, 0, stream>>>(qb, kbuf, vT, ctxg);
  k_gemm<8192, 1280, 1280, 0><<<dim3(64, 10), 256, 0, stream>>>(ctxg, w_outT, b_out, out, nullptr, nullptr, nullptr);
}